// Round 8
// baseline (221.219 us; speedup 1.0000x reference)
//
#include <hip/hip_runtime.h>

// LatticeFilter: step-up (Levinson-Durbin) recursion, rc -> LPC coeffs.
//   rc: (B=16, p=128, Tf=8192) fp32, k_i = 0.98*rc[b,i,t]
//   out: (B, Tf, p+1=129) fp32, a[...,0]=1
//
// R13. R12 post-mortem:
//   - A (28KB text, LDS-governed regalloc) hit its 15us BW floor. I$ model
//     confirmed from the fitting side; allocator recipe (64t block + >=33KB
//     static LDS -> 1 wave/EU -> clean VGPR budget) confirmed (B VGPR=132).
//   - B = 58.4us, IDENTICAL to R8-B (57KB text) despite 26KB text. Shared
//     mechanism isn't code size: it's the STRIDED STATE RELOAD. 90 per-lane
//     loads at stride 516B = 64 cache lines per wave-instruction. Arithmetic:
//     140k cyc / 256 loads ~= 550cy/load -> scatter loads serialize at ~L3
//     latency, one in flight. A's strided WRITES don't stall (fire-and-
//     forget) -> floor. Repeat iters show FETCH~0 (L3-resident): latency,
//     not BW. B's true VALU busy 9.8us = issue floor.
// Fix (B only): bulk-load the block's own 33KB out-region with coalesced
// float4 into the existing LDS buffer (2064 dwordx4, 33/lane, dozens
// outstanding), then per-lane row reads from LDS (bank stride 1 -> free
// 2-way aliasing). Race-free: block X reads exactly the region it writes
// (read at start, write at end, one wave). Garbage cols {0,91..128} are
// loaded and ignored (+20MB read). Bit-identical math (exact fp32 RT).
// Floors: A 94.4MB -> 15us; B 155MB -> 24.6us; predict B 25-30us.

#define NB    16
#define ORD   128
#define TF    8192
#define SPLIT 90

// ---- pair update j <-> m-j, VOP2 v_fmac encoding (4B vs VOP3 fma 8B) ----
// a[J] += k*a[M-J];  a[M-J] += k*a[J]_old   (old copy = 1 v_mov, 4B)
template<int M, int J>
struct PairUpd {
    static __device__ __forceinline__ void run(float (&a)[ORD + 1], float k) {
        const float lo = a[J];                  // old value (one v_mov)
        asm("v_fmac_f32 %0, %1, %2" : "+v"(a[J])     : "v"(k), "v"(a[M - J]));
        asm("v_fmac_f32 %0, %1, %2" : "+v"(a[M - J]) : "v"(k), "v"(lo));
        if constexpr (2 * (J + 1) < M) PairUpd<M, J + 1>::run(a, k);
    }
};

// Steps M..MEND; k from kq[M-1-K0]
template<int M, int MEND, int K0, int NK>
struct Step {
    static __device__ __forceinline__ void run(float (&a)[ORD + 1],
                                               const float (&kq)[NK]) {
        const float k = 0.98f * kq[M - 1 - K0];
        if constexpr (M > 2) PairUpd<M, 1>::run(a, k);
        if constexpr ((M & 1) == 0) {            // middle: a[M/2] += k*a[M/2]
            const float mid = a[M / 2];
            asm("v_fmac_f32 %0, %1, %2" : "+v"(a[M / 2]) : "v"(k), "v"(mid));
        }
        a[M] = k;                                // a[0] == 1 contributes k
        if constexpr (M < MEND) Step<M + 1, MEND, K0, NK>::run(a, kq);
    }
};

// ---- LDS staging, static indices (compiler merges into ds_write_b128) ----
template<int J>
struct Stage {
    static __device__ __forceinline__ void run(float* __restrict__ dst,
                                               const float (&a)[ORD + 1]) {
        dst[J] = a[J];
        if constexpr (J < ORD) Stage<J + 1>::run(dst, a);
    }
};

// ---- LDS state reload, static indices (merges into ds_read2_b32) ----
template<int J>
struct LoadState {
    static __device__ __forceinline__ void run(float (&a)[ORD + 1],
                                               const float* __restrict__ src) {
        a[J] = src[J];
        if constexpr (J < SPLIT) LoadState<J + 1>::run(a, src);
    }
};

// =======================  Kernel A: steps 1..SPLIT  =======================
// ~28KB text < L1I. UNCHANGED from R12 (measured at its 15us BW floor).
// Writes a[1..SPLIT] to out[col*129+j] (final slots; strided stores are
// fire-and-forget -> no wave stall).
__global__ __launch_bounds__(64)
void lpc_stepA(const float* __restrict__ rc, float* __restrict__ out) {
    // 40KB static LDS: occupancy governor (4 blocks/CU -> 1 wave/EU ->
    // full register budget). Kept alive by a ds_write + guarded read.
    __shared__ float lds_gov[64 * 160];

    const int lane = threadIdx.x;                     // 0..63, one wave
    const int col = blockIdx.x * 64 + lane;           // flattened (B*Tf) column
    const int b = col >> 13;
    const int t = col & (TF - 1);
    const float* rcp = rc + ((size_t)b * ORD) * TF + t;

    float kq[SPLIT];                                  // full prefetch: pressure
#pragma unroll                                        // flat (kq dies as a grows)
    for (int i = 0; i < SPLIT; ++i) kq[i] = rcp[(size_t)i * TF];

    float a[ORD + 1];
    a[0] = 1.0f;
    Step<1, SPLIT, 0, SPLIT>::run(a, kq);

    // keep the governor allocation alive (unprovable-but-never-taken read)
    lds_gov[lane] = a[SPLIT];
    __syncthreads();
    if (blockIdx.x == 0xFFFFFFFFu)                    // never true, unprovable
        out[0] = lds_gov[63 - lane];

    // state -> final out positions; strided dwords (L2 aggregates lines)
    float* op = out + (size_t)col * (ORD + 1);
#pragma unroll
    for (int j = 1; j <= SPLIT; ++j) op[j] = a[j];
}

// =====================  Kernel B: steps SPLIT+1..128  =====================
// ~26KB text < L1I. State reload now COALESCED through LDS (the fix).
__global__ __launch_bounds__(64)
void lpc_stepB(const float* __restrict__ rc, float* out) {
    __shared__ __align__(16) float lds[64 * (ORD + 1)];   // 33,024 B
    const int lane = threadIdx.x;                     // 0..63, one wave
    const int col = blockIdx.x * 64 + lane;
    const int b = col >> 13;
    const int t = col & (TF - 1);
    const float* rcp = rc + ((size_t)b * ORD) * TF + t;

    constexpr int NK = ORD - SPLIT;                   // 38 remaining k's
    float kq[NK];
#pragma unroll
    for (int i = 0; i < NK; ++i) kq[i] = rcp[(size_t)(SPLIT + i) * TF];

    // ---- coalesced state reload: own 33KB region -> LDS -> registers ----
    // block X's read region == block X's write region (race-free; single
    // wave: read-at-start, write-at-end). 33 float4 loads per lane, all
    // outstanding; replaces 90 serialized 64-line scatter loads.
    {
        const float4* src4 = (const float4*)(out + (size_t)blockIdx.x * 64 * (ORD + 1));
        float4* dst4 = (float4*)lds;
        for (int e = lane; e < (64 * (ORD + 1)) / 4; e += 64)
            dst4[e] = src4[e];
    }
    __syncthreads();

    float a[ORD + 1];
    a[0] = 1.0f;
    LoadState<1>::run(a, &lds[lane * (ORD + 1)]);     // bank stride 1: free

    Step<SPLIT + 1, ORD, SPLIT, NK>::run(a, kq);

    // ---- epilogue: transpose 64 rows x 129 cols through LDS, 1 round ----
    // (reuses lds; single wave + program order make the overwrite safe,
    //  barrier kept for clarity/safety)
    __syncthreads();
    Stage<0>::run(&lds[lane * (ORD + 1)], a);
    __syncthreads();

    const float4* lds4 = (const float4*)lds;
    float4* out4 = (float4*)(out + (size_t)blockIdx.x * 64 * (ORD + 1));
#pragma unroll 4
    for (int e = lane; e < (64 * (ORD + 1)) / 4; e += 64)
        out4[e] = lds4[e];                            // perfectly coalesced
}

extern "C" void kernel_launch(void* const* d_in, const int* in_sizes, int n_in,
                              void* d_out, int out_size, void* d_ws, size_t ws_size,
                              hipStream_t stream) {
    // d_in[0] = excitation (dead in reference), d_in[1] = rc
    const float* rc = (const float*)d_in[1];
    float* out = (float*)d_out;
    hipLaunchKernelGGL(lpc_stepA, dim3((NB * TF) / 64), dim3(64), 0, stream, rc, out);
    hipLaunchKernelGGL(lpc_stepB, dim3((NB * TF) / 64), dim3(64), 0, stream, rc, out);
}